// Round 1
// baseline (218.032 us; speedup 1.0000x reference)
//
#include <hip/hip_runtime.h>
#include <hip/hip_bf16.h>
#include <hip/hip_fp16.h>

typedef _Float16 half_t;
typedef __attribute__((ext_vector_type(8))) _Float16 half8;
typedef __attribute__((ext_vector_type(4))) _Float16 half4;
typedef __attribute__((ext_vector_type(4))) float floatx4;

#define NJ 24
#define IN_DIM 256
#define HID 128
#define OUT_DIM 6
#define BATCH 16384
#define BM 128  // rows per block

// ws layout (element offsets in half_t for weights, then f32 b3 pad)
#define WT1_ELEMS (NJ * HID * IN_DIM)   // 786432
#define WT2_ELEMS (NJ * HID * HID)      // 393216
#define WT3_ELEMS (NJ * 16 * HID)       // 49152
#define WT2_OFF (WT1_ELEMS)
#define WT3_OFF (WT1_ELEMS + WT2_ELEMS)
#define B3P_BYTE_OFF ((size_t)(WT1_ELEMS + WT2_ELEMS + WT3_ELEMS) * 2)
#define PREP_THREADS (WT1_ELEMS + WT2_ELEMS + WT3_ELEMS + NJ * 16)

// ---------------------------------------------------------------------------
// Prep: convert weights to f16, transposed to [j][n][k]; pad W3/b3 to 16 cols.
// ---------------------------------------------------------------------------
__global__ void posemlp_prep(const float* __restrict__ W1, const float* __restrict__ W2,
                             const float* __restrict__ W3, const float* __restrict__ b3,
                             half_t* __restrict__ wt, float* __restrict__ b3p) {
    int t = blockIdx.x * 256 + threadIdx.x;
    if (t < WT1_ELEMS) {
        int j = t / (HID * IN_DIM);
        int r = t % (HID * IN_DIM);
        int n = r / IN_DIM, k = r % IN_DIM;
        wt[t] = (half_t)W1[((size_t)j * IN_DIM + k) * HID + n];
    } else if (t < WT1_ELEMS + WT2_ELEMS) {
        int u = t - WT1_ELEMS;
        int j = u / (HID * HID);
        int r = u % (HID * HID);
        int n = r / HID, k = r % HID;
        wt[WT2_OFF + u] = (half_t)W2[((size_t)j * HID + k) * HID + n];
    } else if (t < WT1_ELEMS + WT2_ELEMS + WT3_ELEMS) {
        int u = t - WT1_ELEMS - WT2_ELEMS;
        int j = u / (16 * HID);
        int r = u % (16 * HID);
        int n = r / HID, k = r % HID;
        wt[WT3_OFF + u] = (n < OUT_DIM) ? (half_t)W3[((size_t)j * HID + k) * OUT_DIM + n]
                                        : (half_t)0.0f;
    } else if (t < PREP_THREADS) {
        int u = t - WT1_ELEMS - WT2_ELEMS - WT3_ELEMS;
        int j = u / 16, n = u % 16;
        b3p[u] = (n < OUT_DIM) ? b3[j * OUT_DIM + n] : 0.0f;
    }
}

// ---------------------------------------------------------------------------
// helpers
// ---------------------------------------------------------------------------
__device__ inline half8 cvt8(floatx4 a, floatx4 b) {
    half8 h;
    h[0] = (_Float16)a[0]; h[1] = (_Float16)a[1]; h[2] = (_Float16)a[2]; h[3] = (_Float16)a[3];
    h[4] = (_Float16)b[0]; h[5] = (_Float16)b[1]; h[6] = (_Float16)b[2]; h[7] = (_Float16)b[3];
    return h;
}

__device__ inline half8 load_x8(const float* __restrict__ p) {
    floatx4 v0 = *(const floatx4*)p;
    floatx4 v1 = *(const floatx4*)(p + 4);
    return cvt8(v0, v1);
}

// h LDS: [row r (0..127)][n (0..127)] f16, row pitch 256B, XOR-swizzled.
__device__ inline half8 lds_read8(const half_t* lds, int r, int k) {
    int byte = r * 256 + k * 2;
    byte ^= (r & 7) << 4;
    return *(const half8*)((const char*)lds + byte);
}
__device__ inline void lds_write4(half_t* lds, int r, int n, half4 v) {
    int byte = r * 256 + n * 2;
    byte ^= (r & 7) << 4;
    *(half4*)((char*)lds + byte) = v;
}

// ---------------------------------------------------------------------------
// Main: one block per (joint, 128-row tile). 4 waves, each owns 32 rows.
// Computed swapped: D = W^T * X^T so D-frag has n in regs, m in lanes.
// ---------------------------------------------------------------------------
__global__ __launch_bounds__(256) void posemlp_main(
    const float* __restrict__ X, const half_t* __restrict__ wt,
    const float* __restrict__ b1, const float* __restrict__ b2,
    const float* __restrict__ b3p, float* __restrict__ out) {
    __shared__ half_t h_lds[BM * HID];  // 32 KB

    const int bid = blockIdx.x;
    const int j = bid >> 7;       // joint
    const int row0 = (bid & 127) * BM;

    const int tid = threadIdx.x;
    const int w = tid >> 6;
    const int l = tid & 63;
    const int lrow = l & 15;      // m within a 16-frag (also n-row for A frags)
    const int q = l >> 4;         // k-chunk selector

    const half_t* wt1 = wt + (size_t)j * HID * IN_DIM;       // [n][256]
    const half_t* wt2 = wt + WT2_OFF + (size_t)j * HID * HID; // [n2][128]
    const half_t* wt3 = wt + WT3_OFF + (size_t)j * 16 * HID;  // [n3pad][128]

    // this wave's two 16-row groups (mf = 0,1)
    const int rb = w * 32 + lrow;
    const float* xr0 = X + ((size_t)(row0 + rb) * NJ + j) * IN_DIM;
    const float* xr1 = X + ((size_t)(row0 + rb + 16) * NJ + j) * IN_DIM;

    // ---------------- Layer 1: h1 = relu(X*W1 + b1), K=256 ----------------
    floatx4 acc[8][2] = {};
#pragma unroll 2
    for (int ks = 0; ks < 8; ++ks) {
        const int k0 = ks * 32 + q * 8;
        half8 bx0 = load_x8(xr0 + k0);
        half8 bx1 = load_x8(xr1 + k0);
        half8 a[8];
#pragma unroll
        for (int nf = 0; nf < 8; ++nf)
            a[nf] = *(const half8*)(wt1 + (nf * 16 + lrow) * IN_DIM + k0);
#pragma unroll
        for (int nf = 0; nf < 8; ++nf) {
            acc[nf][0] = __builtin_amdgcn_mfma_f32_16x16x32_f16(a[nf], bx0, acc[nf][0], 0, 0, 0);
            acc[nf][1] = __builtin_amdgcn_mfma_f32_16x16x32_f16(a[nf], bx1, acc[nf][1], 0, 0, 0);
        }
    }
    {
        const float* b1j = b1 + j * HID;
#pragma unroll
        for (int nf = 0; nf < 8; ++nf) {
            floatx4 bb = *(const floatx4*)(b1j + nf * 16 + q * 4);
#pragma unroll
            for (int mf = 0; mf < 2; ++mf) {
                floatx4 v = acc[nf][mf];
                half4 hv;
#pragma unroll
                for (int i = 0; i < 4; ++i) hv[i] = (_Float16)fmaxf(v[i] + bb[i], 0.0f);
                lds_write4(h_lds, w * 32 + mf * 16 + lrow, nf * 16 + q * 4, hv);
            }
        }
    }
    __syncthreads();

    // ---------------- Layer 2: h2 = relu(h1*W2 + b2), K=128 ----------------
    floatx4 acc2[8][2] = {};
#pragma unroll 2
    for (int ks = 0; ks < 4; ++ks) {
        const int k0 = ks * 32 + q * 8;
        half8 bf[2];
#pragma unroll
        for (int mf = 0; mf < 2; ++mf)
            bf[mf] = lds_read8(h_lds, w * 32 + mf * 16 + lrow, k0);
#pragma unroll
        for (int nf = 0; nf < 8; ++nf) {
            half8 a = *(const half8*)(wt2 + (nf * 16 + lrow) * HID + k0);
            acc2[nf][0] = __builtin_amdgcn_mfma_f32_16x16x32_f16(a, bf[0], acc2[nf][0], 0, 0, 0);
            acc2[nf][1] = __builtin_amdgcn_mfma_f32_16x16x32_f16(a, bf[1], acc2[nf][1], 0, 0, 0);
        }
    }
    __syncthreads();  // everyone done reading h1
    {
        const float* b2j = b2 + j * HID;
#pragma unroll
        for (int nf = 0; nf < 8; ++nf) {
            floatx4 bb = *(const floatx4*)(b2j + nf * 16 + q * 4);
#pragma unroll
            for (int mf = 0; mf < 2; ++mf) {
                floatx4 v = acc2[nf][mf];
                half4 hv;
#pragma unroll
                for (int i = 0; i < 4; ++i) hv[i] = (_Float16)fmaxf(v[i] + bb[i], 0.0f);
                lds_write4(h_lds, w * 32 + mf * 16 + lrow, nf * 16 + q * 4, hv);
            }
        }
    }
    __syncthreads();

    // ---------------- Layer 3: out = h2*W3 + b3, N padded to 16 ----------------
    floatx4 acc3[2] = {};
#pragma unroll
    for (int ks = 0; ks < 4; ++ks) {
        const int k0 = ks * 32 + q * 8;
        half8 a = *(const half8*)(wt3 + lrow * HID + k0);
#pragma unroll
        for (int mf = 0; mf < 2; ++mf) {
            half8 bf = lds_read8(h_lds, w * 32 + mf * 16 + lrow, k0);
            acc3[mf] = __builtin_amdgcn_mfma_f32_16x16x32_f16(a, bf, acc3[mf], 0, 0, 0);
        }
    }
    {
        floatx4 bb = *(const floatx4*)(b3p + j * 16 + q * 4);  // n3 = q*4 + i
#pragma unroll
        for (int mf = 0; mf < 2; ++mf) {
            const int row = row0 + w * 32 + mf * 16 + lrow;
            float* op = out + ((size_t)row * NJ + j) * OUT_DIM;
            floatx4 v = acc3[mf];
            if (q == 0) {
                float2 s0 = {v[0] + bb[0], v[1] + bb[1]};
                float2 s1 = {v[2] + bb[2], v[3] + bb[3]};
                *(float2*)(op + 0) = s0;
                *(float2*)(op + 2) = s1;
            } else if (q == 1) {
                float2 s = {v[0] + bb[0], v[1] + bb[1]};
                *(float2*)(op + 4) = s;
            }
        }
    }
}

// ---------------------------------------------------------------------------
extern "C" void kernel_launch(void* const* d_in, const int* in_sizes, int n_in,
                              void* d_out, int out_size, void* d_ws, size_t ws_size,
                              hipStream_t stream) {
    const float* X  = (const float*)d_in[0];
    const float* W1 = (const float*)d_in[1];
    const float* b1 = (const float*)d_in[2];
    const float* W2 = (const float*)d_in[3];
    const float* b2 = (const float*)d_in[4];
    const float* W3 = (const float*)d_in[5];
    const float* b3 = (const float*)d_in[6];
    float* out = (float*)d_out;

    half_t* wt = (half_t*)d_ws;
    float* b3p = (float*)((char*)d_ws + B3P_BYTE_OFF);

    int prep_blocks = (PREP_THREADS + 255) / 256;
    posemlp_prep<<<prep_blocks, 256, 0, stream>>>(W1, W2, W3, b3, wt, b3p);

    int grid = NJ * (BATCH / BM);  // 24 * 128 = 3072
    posemlp_main<<<grid, 256, 0, stream>>>(X, wt, b1, b2, b3p, out);
}

// Round 2
// 122.904 us; speedup vs baseline: 1.7740x; 1.7740x over previous
//
#include <hip/hip_runtime.h>
#include <hip/hip_fp16.h>

typedef _Float16 half_t;
typedef __attribute__((ext_vector_type(8))) _Float16 half8;
typedef __attribute__((ext_vector_type(4))) _Float16 half4;
typedef __attribute__((ext_vector_type(4))) float floatx4;

#define NJ 24
#define IN_DIM 256
#define HID 128
#define OUT_DIM 6
#define BATCH 16384
#define BM 128

// ws layout (half elements): W1 [j][ks8][n128][kk32], W2 [j][ks4][n128][kk32],
// W3 [j][n16pad][k128], then f32 b3 padded to 16.
#define W1_JSTRIDE (8 * 128 * 32)
#define W2_JSTRIDE (4 * 128 * 32)
#define W3_JSTRIDE (16 * 128)
#define WT1_ELEMS (NJ * W1_JSTRIDE)
#define WT2_ELEMS (NJ * W2_JSTRIDE)
#define WT3_ELEMS (NJ * W3_JSTRIDE)
#define WT2_OFF WT1_ELEMS
#define WT3_OFF (WT1_ELEMS + WT2_ELEMS)
#define B3P_BYTE_OFF ((size_t)(WT1_ELEMS + WT2_ELEMS + WT3_ELEMS) * 2)
#define PREP_TOTAL (WT1_ELEMS + WT2_ELEMS + WT3_ELEMS + NJ * 16)

// ---------------------------------------------------------------------------
// Prep: f32 -> f16, chunk-major transposed layouts (plain, no swizzle; the
// swizzle is applied on the staging *source* address, m173 pattern).
// ---------------------------------------------------------------------------
__global__ void posemlp_prep(const float* __restrict__ W1, const float* __restrict__ W2,
                             const float* __restrict__ W3, const float* __restrict__ b3,
                             half_t* __restrict__ wt, float* __restrict__ b3p) {
    int t = blockIdx.x * 256 + threadIdx.x;
    if (t < WT1_ELEMS) {
        int j = t / W1_JSTRIDE, r = t % W1_JSTRIDE;
        int ks = r / 4096, r2 = r % 4096;
        int n = r2 / 32, kk = r2 % 32, k = ks * 32 + kk;
        wt[t] = (half_t)W1[((size_t)j * IN_DIM + k) * HID + n];
    } else if (t < WT2_OFF + WT2_ELEMS) {
        int u = t - WT2_OFF;
        int j = u / W2_JSTRIDE, r = u % W2_JSTRIDE;
        int ks = r / 4096, r2 = r % 4096;
        int n = r2 / 32, kk = r2 % 32, k = ks * 32 + kk;
        wt[t] = (half_t)W2[((size_t)j * HID + k) * HID + n];
    } else if (t < WT3_OFF + WT3_ELEMS) {
        int u = t - WT3_OFF;
        int j = u / W3_JSTRIDE, r = u % W3_JSTRIDE;
        int n = r / 128, k = r % 128;
        wt[t] = (n < OUT_DIM) ? (half_t)W3[((size_t)j * HID + k) * OUT_DIM + n] : (half_t)0.0f;
    } else if (t < PREP_TOTAL) {
        int u = t - WT3_OFF - WT3_ELEMS;
        int j = u / 16, n = u % 16;
        b3p[u] = (n < OUT_DIM) ? b3[j * OUT_DIM + n] : 0.0f;
    }
}

// ---------------------------------------------------------------------------
// helpers
// ---------------------------------------------------------------------------
__device__ inline void gll16(const void* g, void* l) {
    __builtin_amdgcn_global_load_lds(
        (const __attribute__((address_space(1))) unsigned int*)g,
        (__attribute__((address_space(3))) unsigned int*)l, 16, 0, 0);
}

#define VMWAIT(N) asm volatile("s_waitcnt vmcnt(" #N ")" ::: "memory")
#define LGKM0()                                     \
    do {                                            \
        asm volatile("s_waitcnt lgkmcnt(0)" ::: "memory"); \
        __builtin_amdgcn_sched_barrier(0);          \
    } while (0)
__device__ inline void barrier_pinned() {
    __builtin_amdgcn_sched_barrier(0);
    __builtin_amdgcn_s_barrier();
    __builtin_amdgcn_sched_barrier(0);
}

// h LDS: [row 0..127][n 0..127] f16, pitch 256B, XOR-swizzled (known-good R0).
__device__ inline half8 lds_read8(const half_t* lds, int r, int k) {
    int byte = r * 256 + k * 2;
    byte ^= (r & 7) << 4;
    return *(const half8*)((const char*)lds + byte);
}
__device__ inline void lds_write4(half_t* lds, int r, int n, half4 v) {
    int byte = r * 256 + n * 2;
    byte ^= (r & 7) << 4;
    *(half4*)((char*)lds + byte) = v;
}

__device__ inline half8 cvt8(floatx4 a, floatx4 b) {
    half8 h;
    h[0] = (_Float16)a[0]; h[1] = (_Float16)a[1]; h[2] = (_Float16)a[2]; h[3] = (_Float16)a[3];
    h[4] = (_Float16)b[0]; h[5] = (_Float16)b[1]; h[6] = (_Float16)b[2]; h[7] = (_Float16)b[3];
    return h;
}

// ---------------------------------------------------------------------------
// Main: 512 threads (8 waves), BM=128 rows, one joint. Wave owns 16 rows.
// Weights stream HBM/L2 -> LDS via async global_load_lds, counted vmcnt(1).
// h is wave-private in LDS -> no layer-boundary barriers.
// ---------------------------------------------------------------------------
__global__ __launch_bounds__(512, 4) void posemlp_main(
    const float* __restrict__ X, const half_t* __restrict__ wt,
    const float* __restrict__ b1, const float* __restrict__ b2,
    const float* __restrict__ b3p, float* __restrict__ out) {
    __shared__ half_t wbuf[2][4096];  // 2 x 8KB weight chunks
    __shared__ half_t w3buf[2048];    // 4KB
    __shared__ half_t h_lds[BM * HID];// 32KB

    const int bid = blockIdx.x;
    const int j = bid >> 7;
    const int row0 = (bid & 127) * BM;
    const int tid = threadIdx.x;
    const int w = tid >> 6;
    const int l = tid & 63;
    const int lrow = l & 15;
    const int q = l >> 4;
    const int myrow = w * 16 + lrow;

    const float* xq = X + ((size_t)(row0 + myrow) * NJ + j) * IN_DIM + q * 8;

    const half_t* w1j = wt + (size_t)j * W1_JSTRIDE;
    const half_t* w2j = wt + WT2_OFF + (size_t)j * W2_JSTRIDE;
    const half_t* w3j = wt + WT3_OFF + (size_t)j * W3_JSTRIDE;

    // staging source indices (per lane; XOR pre-swizzle on source slot)
    const int sn = tid >> 2, ss = tid & 3;
    const int wsrc_off = sn * 32 + (ss ^ ((sn >> 1) & 3)) * 8;  // halves
    half_t* wdst0 = &wbuf[0][w * 512];  // wave-uniform LDS dest
    half_t* wdst1 = &wbuf[1][w * 512];

    // --- prologue: X0 prefetch, stage c0, wt3, c1 ---
    floatx4 px[2][2];
    px[0][0] = *(const floatx4*)(xq);
    px[0][1] = *(const floatx4*)(xq + 4);
    gll16(w1j + wsrc_off, wdst0);
    if (tid < 256) {
        const int tn = tid >> 4, ts = tid & 15;
        gll16(w3j + tn * 128 + (ts ^ tn) * 8, &w3buf[w * 512]);
    }
    gll16(w1j + 4096 + wsrc_off, wdst1);

    // ---------------- Layer 1: K=256, 8 chunks ----------------
    floatx4 acc[8] = {};
#pragma unroll
    for (int ks = 0; ks < 8; ++ks) {
        VMWAIT(1);          // chunk ks + X_ks landed; newest stage stays in flight
        barrier_pinned();
        if (ks < 7) {
            px[(ks + 1) & 1][0] = *(const floatx4*)(xq + (ks + 1) * 32);
            px[(ks + 1) & 1][1] = *(const floatx4*)(xq + (ks + 1) * 32 + 4);
        }
        half8 bx = cvt8(px[ks & 1][0], px[ks & 1][1]);
        const half_t* wb = wbuf[ks & 1];
#pragma unroll
        for (int nf = 0; nf < 8; ++nf) {
            const int n = nf * 16 + lrow;
            half8 a = *(const half8*)&wb[n * 32 + (q ^ ((n >> 1) & 3)) * 8];
            acc[nf] = __builtin_amdgcn_mfma_f32_16x16x32_f16(a, bx, acc[nf], 0, 0, 0);
        }
        LGKM0();            // frag reads complete before buffer reuse
        barrier_pinned();
        if (ks <= 5)      gll16(w1j + (ks + 2) * 4096 + wsrc_off, (ks & 1) ? wdst1 : wdst0);
        else if (ks == 6) gll16(w2j + wsrc_off, wdst0);           // d0
        else              gll16(w2j + 4096 + wsrc_off, wdst1);    // d1
    }
    {   // bias + relu -> h (wave-private rows, no barrier needed)
        const float* b1j = b1 + j * HID;
#pragma unroll
        for (int nf = 0; nf < 8; ++nf) {
            floatx4 bb = *(const floatx4*)(b1j + nf * 16 + q * 4);
            floatx4 v = acc[nf];
            half4 hv;
#pragma unroll
            for (int i = 0; i < 4; ++i) hv[i] = (_Float16)fmaxf(v[i] + bb[i], 0.0f);
            lds_write4(h_lds, myrow, nf * 16 + q * 4, hv);
        }
        LGKM0();
    }

    // ---------------- Layer 2: K=128, 4 chunks ----------------
    floatx4 acc2[8] = {};
#pragma unroll
    for (int ks = 0; ks < 4; ++ks) {
        if (ks == 3) { VMWAIT(0); } else { VMWAIT(1); }
        barrier_pinned();
        half8 bh = lds_read8(h_lds, myrow, ks * 32 + q * 8);
        const half_t* wb = wbuf[ks & 1];
#pragma unroll
        for (int nf = 0; nf < 8; ++nf) {
            const int n = nf * 16 + lrow;
            half8 a = *(const half8*)&wb[n * 32 + (q ^ ((n >> 1) & 3)) * 8];
            acc2[nf] = __builtin_amdgcn_mfma_f32_16x16x32_f16(a, bh, acc2[nf], 0, 0, 0);
        }
        LGKM0();
        barrier_pinned();
        if (ks < 2) gll16(w2j + (ks + 2) * 4096 + wsrc_off, (ks & 1) ? wdst1 : wdst0);
    }
    {   // bias + relu -> h2 (overwrites own rows only; reads drained above)
        const float* b2j = b2 + j * HID;
#pragma unroll
        for (int nf = 0; nf < 8; ++nf) {
            floatx4 bb = *(const floatx4*)(b2j + nf * 16 + q * 4);
            floatx4 v = acc2[nf];
            half4 hv;
#pragma unroll
            for (int i = 0; i < 4; ++i) hv[i] = (_Float16)fmaxf(v[i] + bb[i], 0.0f);
            lds_write4(h_lds, myrow, nf * 16 + q * 4, hv);
        }
        LGKM0();
    }

    // ---------------- Layer 3: N padded to 16, K=128 ----------------
    floatx4 acc3 = {};
#pragma unroll
    for (int ks = 0; ks < 4; ++ks) {
        const int u = ks * 4 + q;
        half8 a3 = *(const half8*)&w3buf[lrow * 128 + (u ^ lrow) * 8];
        half8 bh = lds_read8(h_lds, myrow, ks * 32 + q * 8);
        acc3 = __builtin_amdgcn_mfma_f32_16x16x32_f16(a3, bh, acc3, 0, 0, 0);
    }
    {
        floatx4 bb = *(const floatx4*)(b3p + j * 16 + q * 4);
        const int orow = row0 + myrow;
        float* op = out + ((size_t)orow * NJ + j) * OUT_DIM;
        floatx4 v = acc3;
        if (q == 0) {
            float2 s0 = {v[0] + bb[0], v[1] + bb[1]};
            float2 s1 = {v[2] + bb[2], v[3] + bb[3]};
            *(float2*)(op + 0) = s0;
            *(float2*)(op + 2) = s1;
        } else if (q == 1) {
            float2 s = {v[0] + bb[0], v[1] + bb[1]};
            *(float2*)(op + 4) = s;
        }
    }
}

// ---------------------------------------------------------------------------
extern "C" void kernel_launch(void* const* d_in, const int* in_sizes, int n_in,
                              void* d_out, int out_size, void* d_ws, size_t ws_size,
                              hipStream_t stream) {
    const float* X  = (const float*)d_in[0];
    const float* W1 = (const float*)d_in[1];
    const float* b1 = (const float*)d_in[2];
    const float* W2 = (const float*)d_in[3];
    const float* b2 = (const float*)d_in[4];
    const float* W3 = (const float*)d_in[5];
    const float* b3 = (const float*)d_in[6];
    float* out = (float*)d_out;

    half_t* wt = (half_t*)d_ws;
    float* b3p = (float*)((char*)d_ws + B3P_BYTE_OFF);

    int prep_blocks = (PREP_TOTAL + 255) / 256;
    posemlp_prep<<<prep_blocks, 256, 0, stream>>>(W1, W2, W3, b3, wt, b3p);

    int grid = NJ * (BATCH / BM);  // 3072
    posemlp_main<<<grid, 512, 0, stream>>>(X, wt, b1, b2, b3p, out);
}